// Round 9
// baseline (123.230 us; speedup 1.0000x reference)
//
#include <hip/hip_runtime.h>
#include <math.h>

#define HW    4096
#define NC    32
#define NB    8
#define TINV  10.0f            // 1/TEMP
#define RWIN  8                // window radius; missed sources need |of|>5.5
#define WDIM  (8 + 2 * RWIN)   // 24
#define RCUT  2.5f             // rect cut; excluded normalized weight < 1e-7

// R5 structure verbatim; gather launched 5x as a TIMING PROBE (idempotent:
// plain stores, identical inputs). t_gather = (dur - 74.6) / 4.

__global__ __launch_bounds__(256) void prep_kernel(
    const float* __restrict__ x, const float* __restrict__ of,
    float4* __restrict__ params, float* __restrict__ xt)
{
    __shared__ float tile[32][257];
    int b  = blockIdx.x >> 4;
    int j0 = (blockIdx.x & 15) << 8;
    int t  = threadIdx.x;
    int j  = j0 + t;

    float oy = (float)(j >> 6) + of[(b * 2 + 0) * HW + j];
    float ox = (float)(j & 63) + of[(b * 2 + 1) * HW + j];

    int cy0 = min(max((int)floorf(oy), 0), 63);
    int cx0 = min(max((int)floorf(ox), 0), 63);
    float Dy = 0.f, Dx = 0.f;
    #pragma unroll
    for (int d = -3; d <= 3; ++d) {
        int iy = cy0 + d, ix = cx0 + d;
        if ((unsigned)iy < 64u) Dy += __expf(-TINV * fabsf(oy - (float)iy));
        if ((unsigned)ix < 64u) Dx += __expf(-TINV * fabsf(ox - (float)ix));
    }
    params[(b << 12) + j] = make_float4(oy, ox, 1.f / Dy, 1.f / Dx);

    #pragma unroll
    for (int c = 0; c < NC; ++c)
        tile[c][t] = x[((b * NC + c) << 12) + j];
    __syncthreads();
    #pragma unroll
    for (int k = 0; k < NC; ++k) {
        int o  = k * 256 + t;
        int jj = o >> 5, c = o & 31;
        xt[((size_t)((b << 12) + j0 + jj)) * NC + c] = tile[c][jj];
    }
}

__global__ __launch_bounds__(256) void gather_kernel(
    const float4* __restrict__ params, const float4* __restrict__ xt4,
    float* __restrict__ out)
{
    __shared__ float  red[4 * 64 * 17];
    __shared__ float4 wp[4][64];
    __shared__ int    sj[4][64];

    const int b    = blockIdx.z;
    const int h    = blockIdx.y;
    const int tile = blockIdx.x;
    const int ty0  = (tile >> 3) << 3;
    const int tx0  = (tile & 7) << 3;

    const int tid  = threadIdx.x;
    const int lane = tid & 63;
    const int wv   = __builtin_amdgcn_readfirstlane(tid >> 6);

    const float iy = (float)(ty0 + (lane >> 3));
    const float ix = (float)(tx0 + (lane & 7));

    float acc[16];
    #pragma unroll
    for (int c = 0; c < 16; ++c) acc[c] = 0.f;

    const float4* pb = params + (b << 12);
    const float4* xb = xt4 + (size_t)(b << 12) * 8 + h * 4;

    const int srow = lane >> 5;
    const int scol = lane & 31;

    for (int r = 0; r < 3; ++r) {
        int ry = wv + srow * 4 + r * 8;
        int jy = ty0 - RWIN + ry;
        int jx = tx0 - RWIN + scol;
        bool valid = ((unsigned)jy < 64u) && ((unsigned)jx < 64u) && (scol < WDIM);
        int j = (jy << 6) + jx;
        float4 p = pb[valid ? j : 0];
        float cy = fminf(fmaxf(p.x, 0.f), 63.f);
        float cx = fminf(fmaxf(p.y, 0.f), 63.f);
        float dyr = fmaxf(fmaxf((float)ty0 - cy, cy - ((float)ty0 + 7.f)), 0.f);
        float dxr = fmaxf(fmaxf((float)tx0 - cx, cx - ((float)tx0 + 7.f)), 0.f);
        bool pred = valid && (dyr + dxr < RCUT);

        unsigned long long m = __ballot(pred);
        int cnt = __popcll(m);
        if (pred) {
            int pos = __builtin_amdgcn_mbcnt_hi((unsigned)(m >> 32),
                      __builtin_amdgcn_mbcnt_lo((unsigned)m, 0u));
            wp[wv][pos] = p;
            sj[wv][pos] = j;
        }

        for (int k = 0; k < cnt; k += 4) {
            int i1 = min(k + 1, cnt - 1);
            int i2 = min(k + 2, cnt - 1);
            int i3 = min(k + 3, cnt - 1);
            float4 p0 = wp[wv][k],  p1 = wp[wv][i1];
            float4 p2 = wp[wv][i2], p3 = wp[wv][i3];
            int j0 = __builtin_amdgcn_readfirstlane(sj[wv][k]);
            int j1 = __builtin_amdgcn_readfirstlane(sj[wv][i1]);
            int j2 = __builtin_amdgcn_readfirstlane(sj[wv][i2]);
            int j3 = __builtin_amdgcn_readfirstlane(sj[wv][i3]);

            const float4* x0 = xb + j0 * 8;
            const float4* x1 = xb + j1 * 8;
            const float4* x2 = xb + j2 * 8;
            const float4* x3 = xb + j3 * 8;
            float4 A[4], B[4], C[4], D[4];
            #pragma unroll
            for (int u = 0; u < 4; ++u) A[u] = x0[u];
            #pragma unroll
            for (int u = 0; u < 4; ++u) B[u] = x1[u];
            #pragma unroll
            for (int u = 0; u < 4; ++u) C[u] = x2[u];
            #pragma unroll
            for (int u = 0; u < 4; ++u) D[u] = x3[u];

            float g0 = (__expf(-TINV * fabsf(p0.x - iy)) * p0.z)
                     * (__expf(-TINV * fabsf(p0.y - ix)) * p0.w);
            float g1 = (__expf(-TINV * fabsf(p1.x - iy)) * p1.z)
                     * (__expf(-TINV * fabsf(p1.y - ix)) * p1.w);
            float g2 = (__expf(-TINV * fabsf(p2.x - iy)) * p2.z)
                     * (__expf(-TINV * fabsf(p2.y - ix)) * p2.w);
            float g3 = (__expf(-TINV * fabsf(p3.x - iy)) * p3.z)
                     * (__expf(-TINV * fabsf(p3.y - ix)) * p3.w);
            g1 = (k + 1 < cnt) ? g1 : 0.f;
            g2 = (k + 2 < cnt) ? g2 : 0.f;
            g3 = (k + 3 < cnt) ? g3 : 0.f;

            #pragma unroll
            for (int u = 0; u < 4; ++u) {
                acc[4*u+0] = fmaf(g0, A[u].x, acc[4*u+0]);
                acc[4*u+1] = fmaf(g0, A[u].y, acc[4*u+1]);
                acc[4*u+2] = fmaf(g0, A[u].z, acc[4*u+2]);
                acc[4*u+3] = fmaf(g0, A[u].w, acc[4*u+3]);
            }
            #pragma unroll
            for (int u = 0; u < 4; ++u) {
                acc[4*u+0] = fmaf(g1, B[u].x, acc[4*u+0]);
                acc[4*u+1] = fmaf(g1, B[u].y, acc[4*u+1]);
                acc[4*u+2] = fmaf(g1, B[u].z, acc[4*u+2]);
                acc[4*u+3] = fmaf(g1, B[u].w, acc[4*u+3]);
            }
            #pragma unroll
            for (int u = 0; u < 4; ++u) {
                acc[4*u+0] = fmaf(g2, C[u].x, acc[4*u+0]);
                acc[4*u+1] = fmaf(g2, C[u].y, acc[4*u+1]);
                acc[4*u+2] = fmaf(g2, C[u].z, acc[4*u+2]);
                acc[4*u+3] = fmaf(g2, C[u].w, acc[4*u+3]);
            }
            #pragma unroll
            for (int u = 0; u < 4; ++u) {
                acc[4*u+0] = fmaf(g3, D[u].x, acc[4*u+0]);
                acc[4*u+1] = fmaf(g3, D[u].y, acc[4*u+1]);
                acc[4*u+2] = fmaf(g3, D[u].z, acc[4*u+2]);
                acc[4*u+3] = fmaf(g3, D[u].w, acc[4*u+3]);
            }
        }
    }

    float* myred = red + (wv * 64 + lane) * 17;
    #pragma unroll
    for (int c = 0; c < 16; ++c) myred[c] = acc[c];
    __syncthreads();

    int c   = tid >> 4;
    int t16 = tid & 15;
    #pragma unroll
    for (int k = 0; k < 4; ++k) {
        int t = t16 + 16 * k;
        float s = red[(0 * 64 + t) * 17 + c]
                + red[(1 * 64 + t) * 17 + c]
                + red[(2 * 64 + t) * 17 + c]
                + red[(3 * 64 + t) * 17 + c];
        int ch = h * 16 + c;
        out[(((b << 5) + ch) << 12) + (ty0 + (t >> 3)) * 64 + (tx0 + (t & 7))] = s;
    }
}

extern "C" void kernel_launch(void* const* d_in, const int* in_sizes, int n_in,
                              void* d_out, int out_size, void* d_ws, size_t ws_size,
                              hipStream_t stream) {
    const float* x  = (const float*)d_in[0];   // [8,32,64,64]
    const float* of = (const float*)d_in[1];   // [8,2,64,64]
    float* out = (float*)d_out;                // [8,32,64,64] fp32

    float4* params = (float4*)d_ws;                                    // 512 KB
    float*  xt     = (float*)((char*)d_ws + NB * HW * sizeof(float4)); // 4 MB

    prep_kernel<<<dim3(NB * 16), dim3(256), 0, stream>>>(x, of, params, xt);
    // TIMING PROBE: 5 idempotent launches; t_gather = (dur_us - 74.6) / 4
    for (int rep = 0; rep < 5; ++rep)
        gather_kernel<<<dim3(64, 2, NB), dim3(256), 0, stream>>>(
            params, (const float4*)xt, out);
}

// Round 10
// 72.408 us; speedup vs baseline: 1.7019x; 1.7019x over previous
//
#include <hip/hip_runtime.h>
#include <math.h>

#define HW    4096
#define NC    32
#define NB    8
#define TINV  10.0f            // 1/TEMP
#define RWIN  8                // window radius; missed sources need |of|>5.5
#define WDIM  (8 + 2 * RWIN)   // 24
#define RCUT  2.5f             // rect cut; excluded normalized weight < 1e-7

// ws layout: params (float4 per b*HW) then xt (transposed x, [b][j][c])

__global__ __launch_bounds__(256) void prep_kernel(
    const float* __restrict__ x, const float* __restrict__ of,
    float4* __restrict__ params, float* __restrict__ xt)
{
    __shared__ float tile[32][257];
    int b  = blockIdx.x >> 4;
    int j0 = (blockIdx.x & 15) << 8;
    int t  = threadIdx.x;
    int j  = j0 + t;

    float oy = (float)(j >> 6) + of[(b * 2 + 0) * HW + j];
    float ox = (float)(j & 63) + of[(b * 2 + 1) * HW + j];

    // truncated denominators: omitted terms < e^-25 relative
    int cy0 = min(max((int)floorf(oy), 0), 63);
    int cx0 = min(max((int)floorf(ox), 0), 63);
    float Dy = 0.f, Dx = 0.f;
    #pragma unroll
    for (int d = -3; d <= 3; ++d) {
        int iy = cy0 + d, ix = cx0 + d;
        if ((unsigned)iy < 64u) Dy += __expf(-TINV * fabsf(oy - (float)iy));
        if ((unsigned)ix < 64u) Dx += __expf(-TINV * fabsf(ox - (float)ix));
    }
    params[(b << 12) + j] = make_float4(oy, ox, 1.f / Dy, 1.f / Dx);

    #pragma unroll
    for (int c = 0; c < NC; ++c)
        tile[c][t] = x[((b * NC + c) << 12) + j];
    __syncthreads();
    #pragma unroll
    for (int k = 0; k < NC; ++k) {
        int o  = k * 256 + t;
        int jj = o >> 5, c = o & 31;
        xt[((size_t)((b << 12) + j0 + jj)) * NC + c] = tile[c][jj];
    }
}

// grid: (64 tiles, 2 channel-halves, 8 batches); 16 channels per block
__global__ __launch_bounds__(256) void gather_kernel(
    const float4* __restrict__ params, const float4* __restrict__ xt4,
    float* __restrict__ out)
{
    __shared__ float4 wp[4][64];          //  4 KB  survivor params
    __shared__ int    sj[4][64];          //  1 KB  survivor source idx
    __shared__ float  pool[4 * 64 * 17];  // 17 KB: XS (staging) then red

    const int b    = blockIdx.z;
    const int h    = blockIdx.y;          // channel half
    const int tile = blockIdx.x;
    const int ty0  = (tile >> 3) << 3;
    const int tx0  = (tile & 7) << 3;

    const int tid  = threadIdx.x;
    const int lane = tid & 63;
    const int wv   = __builtin_amdgcn_readfirstlane(tid >> 6);

    const float iy = (float)(ty0 + (lane >> 3));
    const float ix = (float)(tx0 + (lane & 7));

    float acc[16];
    #pragma unroll
    for (int c = 0; c < 16; ++c) acc[c] = 0.f;

    const float4* pb = params + (b << 12);
    const float4* xb = xt4 + (size_t)(b << 12) * 8 + h * 4;  // 16 ch @ half h

    const int srow = lane >> 5;           // 2 window rows x 32 cols per round
    const int scol = lane & 31;
    const int sidq = lane >> 2;           // staging: survivor id (0..15)
    const int quad = lane & 3;            // staging: float4 quad within 64 B

    float* XS = pool;                     // [wv][s][16] floats, stride 16

    for (int r = 0; r < 3; ++r) {
        // ---- screen 64 candidates ----
        int ry = wv + srow * 4 + r * 8;   // all 24 rows over 4 waves
        int jy = ty0 - RWIN + ry;
        int jx = tx0 - RWIN + scol;
        bool valid = ((unsigned)jy < 64u) && ((unsigned)jx < 64u) && (scol < WDIM);
        int j = (jy << 6) + jx;
        float4 p = pb[valid ? j : 0];
        float cy = fminf(fmaxf(p.x, 0.f), 63.f);
        float cx = fminf(fmaxf(p.y, 0.f), 63.f);
        float dyr = fmaxf(fmaxf((float)ty0 - cy, cy - ((float)ty0 + 7.f)), 0.f);
        float dxr = fmaxf(fmaxf((float)tx0 - cx, cx - ((float)tx0 + 7.f)), 0.f);
        bool pred = valid && (dyr + dxr < RCUT);

        unsigned long long m = __ballot(pred);
        int cnt = __popcll(m);
        if (pred) {
            int pos = __builtin_amdgcn_mbcnt_hi((unsigned)(m >> 32),
                      __builtin_amdgcn_mbcnt_lo((unsigned)m, 0u));
            wp[wv][pos] = p;
            sj[wv][pos] = j;
        }

        // ---- stage survivors' x into LDS: lane-parallel loads, 16 surv/pass
        //      (16 x 64 B cache lines in flight per load instruction) ----
        for (int m4 = 0; m4 < cnt; m4 += 16) {
            int s = sidq + m4;            // this lane's survivor
            if (s < cnt) {
                int jj = sj[wv][s];       // 4-lane groups same addr: broadcast
                float4 v = xb[jj * 8 + quad];
                *(float4*)&XS[((wv << 6) + s) * 16 + (quad << 2)] = v;
            }
        }

        // ---- FMA over survivors, 2-wide, all operands from LDS ----
        for (int k = 0; k < cnt; k += 2) {
            int i1 = min(k + 1, cnt - 1);
            float4 p0 = wp[wv][k], p1 = wp[wv][i1];
            const float* x0 = &XS[((wv << 6) + k)  * 16];
            const float* x1 = &XS[((wv << 6) + i1) * 16];
            float4 A[4], B[4];
            #pragma unroll
            for (int u = 0; u < 4; ++u) A[u] = ((const float4*)x0)[u];
            #pragma unroll
            for (int u = 0; u < 4; ++u) B[u] = ((const float4*)x1)[u];

            // per-dim normalize before product (fp32 overflow safety for OOB)
            float g0 = (__expf(-TINV * fabsf(p0.x - iy)) * p0.z)
                     * (__expf(-TINV * fabsf(p0.y - ix)) * p0.w);
            float g1 = (__expf(-TINV * fabsf(p1.x - iy)) * p1.z)
                     * (__expf(-TINV * fabsf(p1.y - ix)) * p1.w);
            g1 = (k + 1 < cnt) ? g1 : 0.f;

            #pragma unroll
            for (int u = 0; u < 4; ++u) {
                acc[4*u+0] = fmaf(g0, A[u].x, acc[4*u+0]);
                acc[4*u+1] = fmaf(g0, A[u].y, acc[4*u+1]);
                acc[4*u+2] = fmaf(g0, A[u].z, acc[4*u+2]);
                acc[4*u+3] = fmaf(g0, A[u].w, acc[4*u+3]);
            }
            #pragma unroll
            for (int u = 0; u < 4; ++u) {
                acc[4*u+0] = fmaf(g1, B[u].x, acc[4*u+0]);
                acc[4*u+1] = fmaf(g1, B[u].y, acc[4*u+1]);
                acc[4*u+2] = fmaf(g1, B[u].z, acc[4*u+2]);
                acc[4*u+3] = fmaf(g1, B[u].w, acc[4*u+3]);
            }
        }
    }

    // ---- cross-wave reduction; red overlays XS (all XS reads done) ----
    __syncthreads();
    float* red = pool;                    // stride 17 -> at most 2-way = free
    float* myred = red + ((wv << 6) + lane) * 17;
    #pragma unroll
    for (int c = 0; c < 16; ++c) myred[c] = acc[c];
    __syncthreads();

    int c   = tid >> 4;                   // 0..15
    int t16 = tid & 15;
    #pragma unroll
    for (int k = 0; k < 4; ++k) {
        int t = t16 + 16 * k;
        float s = red[(0 * 64 + t) * 17 + c]
                + red[(1 * 64 + t) * 17 + c]
                + red[(2 * 64 + t) * 17 + c]
                + red[(3 * 64 + t) * 17 + c];
        int ch = h * 16 + c;
        out[(((b << 5) + ch) << 12) + (ty0 + (t >> 3)) * 64 + (tx0 + (t & 7))] = s;
    }
}

extern "C" void kernel_launch(void* const* d_in, const int* in_sizes, int n_in,
                              void* d_out, int out_size, void* d_ws, size_t ws_size,
                              hipStream_t stream) {
    const float* x  = (const float*)d_in[0];   // [8,32,64,64]
    const float* of = (const float*)d_in[1];   // [8,2,64,64]
    float* out = (float*)d_out;                // [8,32,64,64] fp32

    float4* params = (float4*)d_ws;                                    // 512 KB
    float*  xt     = (float*)((char*)d_ws + NB * HW * sizeof(float4)); // 4 MB

    prep_kernel<<<dim3(NB * 16), dim3(256), 0, stream>>>(x, of, params, xt);
    gather_kernel<<<dim3(64, 2, NB), dim3(256), 0, stream>>>(params, (const float4*)xt, out);
}